// Round 5
// baseline (150.735 us; speedup 1.0000x reference)
//
#include <hip/hip_runtime.h>

#define B_    16
#define CIN_  128
#define COUT_ 128
#define N_    4096
#define K_    16

typedef __attribute__((ext_vector_type(8))) short bf16x8;  // 8 bf16 = 4 VGPR
typedef __attribute__((ext_vector_type(4))) float f32x4;
typedef __attribute__((ext_vector_type(4))) int   i32x4;
typedef __attribute__((ext_vector_type(2))) float f32x2;

__device__ inline unsigned short f2bf(float f) {  // round-to-nearest-even
  unsigned u = __float_as_uint(f);
  u += 0x7fffu + ((u >> 16) & 1u);
  return (unsigned short)(u >> 16);
}

// XCD-affinity: dispatch is round-robin over 8 XCDs by linear block id, so
// batch b is pinned to XCD b>>1 in BOTH kernels -> gemm produces h[b] into the
// same XCD L2 (4 MB for 2 bf16 slabs) that aggr gathers from.
// ---------------------------------------------------------------------------
// Kernel 1: h[b][n][co] = bf16(relu(sum_ci W[co][ci]*x[b][ci][n]))
// 1024 blocks x 256 thr; tile 64n x 128co, full K=128; wave w owns 16 n.
// W: fp32 global -> bf16 LDS (+8 pad rows -> conflict-free b128 reads).
// A-frags straight from global (16 lanes hit one 64B line per ci).
// ---------------------------------------------------------------------------
__global__ __launch_bounds__(256) void gemm_relu_k(
    const float* __restrict__ x, const float* __restrict__ W,
    unsigned short* __restrict__ h) {
  __shared__ unsigned short Wl[128 * 136];  // [co][ci], +8 pad
  const int tid = threadIdx.x;
  const int l   = blockIdx.x;
  const int b   = ((l & 7) << 1) | ((l >> 3) >> 6);
  const int n0  = ((l >> 3) & 63) * 64;

  // ---- stage W -> bf16 LDS (coalesced float4 reads, b64 LDS writes) ----
#pragma unroll
  for (int r = 0; r < 16; ++r) {
    int id = tid + 256 * r;   // 0..4095 float4s
    int co = id >> 5;
    int cq = id & 31;         // float4 index along ci
    float4 v = reinterpret_cast<const float4*>(W)[id];
    unsigned p0 = (unsigned)f2bf(v.x) | ((unsigned)f2bf(v.y) << 16);
    unsigned p1 = (unsigned)f2bf(v.z) | ((unsigned)f2bf(v.w) << 16);
    *reinterpret_cast<uint2*>(&Wl[co * 136 + 4 * cq]) = make_uint2(p0, p1);
  }
  __syncthreads();

  const int lane = tid & 63;
  const int w    = tid >> 6;
  const int m    = lane & 15;
  const int quad = lane >> 4;

  // ---- A-fragments straight from global ----
  const float* xb = x + (size_t)b * CIN_ * N_ + n0 + 16 * w + m;
  bf16x8 a[4];
#pragma unroll
  for (int s = 0; s < 4; ++s) {
#pragma unroll
    for (int j = 0; j < 8; ++j) {
      int ci = 32 * s + 8 * quad + j;
      a[s][j] = (short)f2bf(xb[(size_t)ci * N_]);
    }
  }

  const int rbase = n0 + 16 * w + 4 * quad;
  unsigned short* hb = h + (size_t)b * N_ * COUT_;
#pragma unroll
  for (int t = 0; t < 8; ++t) {   // 8 co-tiles of 16
    f32x4 c = {0.f, 0.f, 0.f, 0.f};
#pragma unroll
    for (int s = 0; s < 4; ++s) { // K = 4 x 32
      bf16x8 bf = *reinterpret_cast<const bf16x8*>(
          &Wl[(16 * t + m) * 136 + 32 * s + 8 * quad]);
      c = __builtin_amdgcn_mfma_f32_16x16x32_bf16(a[s], bf, c, 0, 0, 0);
    }
    int co = 16 * t + m;
#pragma unroll
    for (int r = 0; r < 4; ++r) {
      float v = c[r] > 0.f ? c[r] : 0.f;  // ReLU
      hb[(size_t)(rbase + r) * COUT_ + co] = f2bf(v);
    }
  }
}

// ---------------------------------------------------------------------------
// Kernel 2: out[b][co][n] = (sum_k h[b][idx[n,k]][:] + h[b][n][:])/17 + bias
// 2048 blocks x 256 thr, single launch; b = 2*(l&7)+bit -> 2 slabs per XCD L2.
// Tile 32n x 128co; q=tid&15 -> 8 co (16B gather: 16 lanes = full 256B row),
// g=tid>>4 -> 2 n. NT ei loads / NT out stores protect h residency in L2.
// ---------------------------------------------------------------------------
__global__ __launch_bounds__(256) void aggr_k(
    const unsigned short* __restrict__ h, const int* __restrict__ ei,
    const float* __restrict__ bias, float* __restrict__ out) {
  __shared__ int idx_t[K_ * 32];  // [k][n] transposed
  const int tid  = threadIdx.x;
  const int l    = blockIdx.x;
  const int rest = l >> 3;                       // 0..255
  const int b    = ((l & 7) << 1) | (rest >> 7);
  const int n0   = (rest & 127) * 32;

  if (tid < 128) {  // stage+transpose neighbor indices (coalesced int4, NT)
    int n  = tid >> 2;       // 0..31
    int kq = tid & 3;        // int4 along k
    i32x4 v = __builtin_nontemporal_load(
        reinterpret_cast<const i32x4*>(ei + ((size_t)b * N_ + n0 + n) * K_) + kq);
    idx_t[(4 * kq + 0) * 32 + n] = v.x;
    idx_t[(4 * kq + 1) * 32 + n] = v.y;
    idx_t[(4 * kq + 2) * 32 + n] = v.z;
    idx_t[(4 * kq + 3) * 32 + n] = v.w;
  }
  __syncthreads();

  const int q = tid & 15;   // co = 8q..8q+7
  const int g = tid >> 4;   // n_local = 2g, 2g+1
  const unsigned short* hb = h + (size_t)b * N_ * COUT_;

  float acc[2][8];
#pragma unroll
  for (int j = 0; j < 2; ++j) {  // self-loop term
    uint4 v = *reinterpret_cast<const uint4*>(
        hb + (size_t)(n0 + 2 * g + j) * COUT_ + 8 * q);
    acc[j][0] = __uint_as_float(v.x << 16);
    acc[j][1] = __uint_as_float(v.x & 0xffff0000u);
    acc[j][2] = __uint_as_float(v.y << 16);
    acc[j][3] = __uint_as_float(v.y & 0xffff0000u);
    acc[j][4] = __uint_as_float(v.z << 16);
    acc[j][5] = __uint_as_float(v.z & 0xffff0000u);
    acc[j][6] = __uint_as_float(v.w << 16);
    acc[j][7] = __uint_as_float(v.w & 0xffff0000u);
  }
#pragma unroll 4
  for (int k = 0; k < K_; ++k) {
    int2 jj = *reinterpret_cast<const int2*>(&idx_t[k * 32 + 2 * g]);
#pragma unroll
    for (int j = 0; j < 2; ++j) {
      int node = (j == 0) ? jj.x : jj.y;
      uint4 v = *reinterpret_cast<const uint4*>(
          hb + (size_t)node * COUT_ + 8 * q);
      acc[j][0] += __uint_as_float(v.x << 16);
      acc[j][1] += __uint_as_float(v.x & 0xffff0000u);
      acc[j][2] += __uint_as_float(v.y << 16);
      acc[j][3] += __uint_as_float(v.y & 0xffff0000u);
      acc[j][4] += __uint_as_float(v.z << 16);
      acc[j][5] += __uint_as_float(v.z & 0xffff0000u);
      acc[j][6] += __uint_as_float(v.w << 16);
      acc[j][7] += __uint_as_float(v.w & 0xffff0000u);
    }
  }

  const float norm = 1.0f / 17.0f;
  const float4 bv0 = *reinterpret_cast<const float4*>(bias + 8 * q);
  const float4 bv1 = *reinterpret_cast<const float4*>(bias + 8 * q + 4);
  float* ob = out + (size_t)b * COUT_ * N_ + n0 + 2 * g;
#pragma unroll
  for (int c = 0; c < 8; ++c) {
    int co = 8 * q + c;
    float bb = (c < 4) ? ((c == 0) ? bv0.x : (c == 1) ? bv0.y : (c == 2) ? bv0.z : bv0.w)
                       : ((c == 4) ? bv1.x : (c == 5) ? bv1.y : (c == 6) ? bv1.z : bv1.w);
    f32x2 r;
    r.x = acc[0][c] * norm + bb;
    r.y = acc[1][c] * norm + bb;
    __builtin_nontemporal_store(r, reinterpret_cast<f32x2*>(ob + (size_t)co * N_));
  }
}

extern "C" void kernel_launch(void* const* d_in, const int* in_sizes, int n_in,
                              void* d_out, int out_size, void* d_ws, size_t ws_size,
                              hipStream_t stream) {
  const float* x    = (const float*)d_in[0];
  const int*   ei   = (const int*)d_in[1];   // [2][B][N][K]; plane 0
  const float* W    = (const float*)d_in[2];
  const float* bias = (const float*)d_in[3];
  float* out = (float*)d_out;
  unsigned short* h = (unsigned short*)d_ws;  // B*N*COUT*2 = 16 MB bf16

  gemm_relu_k<<<dim3(B_ * N_ / 64), 256, 0, stream>>>(x, W, h);
  aggr_k<<<dim3(B_ * N_ / 32), 256, 0, stream>>>(h, ei, bias, out);
}

// Round 6
// 116.352 us; speedup vs baseline: 1.2955x; 1.2955x over previous
//
#include <hip/hip_runtime.h>

#define B_    16
#define CIN_  128
#define COUT_ 128
#define N_    4096
#define K_    16

typedef __attribute__((ext_vector_type(8))) short bf16x8;  // 8 bf16 = 4 VGPR
typedef __attribute__((ext_vector_type(4))) float f32x4;
typedef __attribute__((ext_vector_type(4))) int   i32x4;

__device__ inline unsigned short f2bf(float f) {  // round-to-nearest-even
  unsigned u = __float_as_uint(f);
  u += 0x7fffu + ((u >> 16) & 1u);
  return (unsigned short)(u >> 16);
}

// XCD-affinity: dispatch is round-robin over 8 XCDs by linear block id, so
// batch b is pinned to XCD b>>1 in BOTH kernels -> gemm produces h[b] into the
// same XCD L2 (4 MB = two 2 MB bf16 slabs) that aggr gathers from.
// ---------------------------------------------------------------------------
// Kernel 1: h[b][n][co] = bf16(relu(sum_ci W[co][ci]*x[b][ci][n]))
// 1024 blocks x 256 thr; tile 64n x 128co, full K=128; wave w owns 16 n.
// W: fp32 global -> bf16 LDS (+8 pad rows -> conflict-free b128 reads).
// A-frags straight from global (16 lanes hit one 64B line per ci).
// ---------------------------------------------------------------------------
__global__ __launch_bounds__(256) void gemm_relu_k(
    const float* __restrict__ x, const float* __restrict__ W,
    unsigned short* __restrict__ h) {
  __shared__ unsigned short Wl[128 * 136];  // [co][ci], +8 pad
  const int tid = threadIdx.x;
  const int l   = blockIdx.x;
  const int b   = ((l & 7) << 1) | ((l >> 3) >> 6);
  const int n0  = ((l >> 3) & 63) * 64;

  // ---- stage W -> bf16 LDS (coalesced float4 reads, b64 LDS writes) ----
#pragma unroll
  for (int r = 0; r < 16; ++r) {
    int id = tid + 256 * r;   // 0..4095 float4s
    int co = id >> 5;
    int cq = id & 31;         // float4 index along ci
    float4 v = reinterpret_cast<const float4*>(W)[id];
    unsigned p0 = (unsigned)f2bf(v.x) | ((unsigned)f2bf(v.y) << 16);
    unsigned p1 = (unsigned)f2bf(v.z) | ((unsigned)f2bf(v.w) << 16);
    *reinterpret_cast<uint2*>(&Wl[co * 136 + 4 * cq]) = make_uint2(p0, p1);
  }
  __syncthreads();

  const int lane = tid & 63;
  const int w    = tid >> 6;
  const int m    = lane & 15;
  const int quad = lane >> 4;

  // ---- A-fragments straight from global ----
  const float* xb = x + (size_t)b * CIN_ * N_ + n0 + 16 * w + m;
  bf16x8 a[4];
#pragma unroll
  for (int s = 0; s < 4; ++s) {
#pragma unroll
    for (int j = 0; j < 8; ++j) {
      int ci = 32 * s + 8 * quad + j;
      a[s][j] = (short)f2bf(xb[(size_t)ci * N_]);
    }
  }

  const int rbase = n0 + 16 * w + 4 * quad;
  unsigned short* hb = h + (size_t)b * N_ * COUT_;
#pragma unroll
  for (int t = 0; t < 8; ++t) {   // 8 co-tiles of 16
    f32x4 c = {0.f, 0.f, 0.f, 0.f};
#pragma unroll
    for (int s = 0; s < 4; ++s) { // K = 4 x 32
      bf16x8 bf = *reinterpret_cast<const bf16x8*>(
          &Wl[(16 * t + m) * 136 + 32 * s + 8 * quad]);
      c = __builtin_amdgcn_mfma_f32_16x16x32_bf16(a[s], bf, c, 0, 0, 0);
    }
    int co = 16 * t + m;
#pragma unroll
    for (int r = 0; r < 4; ++r) {
      float v = c[r] > 0.f ? c[r] : 0.f;  // ReLU
      hb[(size_t)(rbase + r) * COUT_ + co] = f2bf(v);
    }
  }
}

// ---------------------------------------------------------------------------
// Kernel 2: out[b][co][n] = (sum_{17} h[b][idx'][:])/17 + bias, idx' incl self
// 1024 blocks x 256 thr; tile 64n x 128co; same XCD mapping as gemm.
// q=tid&15 -> 8 co (16B gather: 16 lanes = one 256B h row), g=tid>>4 -> 4 n.
// 4 independent gathers per k, unroll-2 over k, VGPR cap 128 -> ~8 in flight.
// Plain cached stores (NT stores caused 2x HBM write amplification in R5).
// ---------------------------------------------------------------------------
__global__ __launch_bounds__(256, 4) void aggr_k(
    const unsigned short* __restrict__ h, const int* __restrict__ ei,
    const float* __restrict__ bias, float* __restrict__ out) {
  __shared__ int idx_t[17 * 64];  // [k][n], k=16 is the self loop
  const int tid  = threadIdx.x;
  const int l    = blockIdx.x;
  const int rest = l >> 3;                        // 0..127
  const int b    = ((l & 7) << 1) | (rest >> 6);
  const int n0   = (rest & 63) * 64;

  {  // stage+transpose neighbor indices (coalesced int4, NT to spare L2)
    int n  = tid >> 2;       // 0..63
    int kq = tid & 3;        // int4 along k
    i32x4 v = __builtin_nontemporal_load(
        reinterpret_cast<const i32x4*>(ei + ((size_t)b * N_ + n0 + n) * K_) + kq);
    idx_t[(4 * kq + 0) * 64 + n] = v.x;
    idx_t[(4 * kq + 1) * 64 + n] = v.y;
    idx_t[(4 * kq + 2) * 64 + n] = v.z;
    idx_t[(4 * kq + 3) * 64 + n] = v.w;
    if (tid < 64) idx_t[16 * 64 + tid] = n0 + tid;  // self loop
  }
  __syncthreads();

  const int q = tid & 15;   // co = 8q..8q+7
  const int g = tid >> 4;   // n_local = 4g .. 4g+3
  const unsigned short* hb = h + (size_t)b * N_ * COUT_;

  float acc[4][8];
#pragma unroll
  for (int j = 0; j < 4; ++j)
#pragma unroll
    for (int c = 0; c < 8; ++c) acc[j][c] = 0.f;

#pragma unroll 2
  for (int k = 0; k < 17; ++k) {
    uint4 v[4];
#pragma unroll
    for (int j = 0; j < 4; ++j) {
      int node = idx_t[k * 64 + 4 * g + j];
      v[j] = *reinterpret_cast<const uint4*>(hb + (size_t)node * COUT_ + 8 * q);
    }
#pragma unroll
    for (int j = 0; j < 4; ++j) {
      acc[j][0] += __uint_as_float(v[j].x << 16);
      acc[j][1] += __uint_as_float(v[j].x & 0xffff0000u);
      acc[j][2] += __uint_as_float(v[j].y << 16);
      acc[j][3] += __uint_as_float(v[j].y & 0xffff0000u);
      acc[j][4] += __uint_as_float(v[j].z << 16);
      acc[j][5] += __uint_as_float(v[j].z & 0xffff0000u);
      acc[j][6] += __uint_as_float(v[j].w << 16);
      acc[j][7] += __uint_as_float(v[j].w & 0xffff0000u);
    }
  }

  const float norm = 1.0f / 17.0f;
  const float4 bv0 = *reinterpret_cast<const float4*>(bias + 8 * q);
  const float4 bv1 = *reinterpret_cast<const float4*>(bias + 8 * q + 4);
  float* ob = out + (size_t)b * COUT_ * N_ + n0 + 4 * g;
#pragma unroll
  for (int c = 0; c < 8; ++c) {
    int co = 8 * q + c;
    float bb = (c < 4) ? ((c == 0) ? bv0.x : (c == 1) ? bv0.y : (c == 2) ? bv0.z : bv0.w)
                       : ((c == 4) ? bv1.x : (c == 5) ? bv1.y : (c == 6) ? bv1.z : bv1.w);
    float4 r;
    r.x = acc[0][c] * norm + bb;
    r.y = acc[1][c] * norm + bb;
    r.z = acc[2][c] * norm + bb;
    r.w = acc[3][c] * norm + bb;
    *reinterpret_cast<float4*>(ob + (size_t)co * N_) = r;  // 16B, 64B/segment
  }
}

extern "C" void kernel_launch(void* const* d_in, const int* in_sizes, int n_in,
                              void* d_out, int out_size, void* d_ws, size_t ws_size,
                              hipStream_t stream) {
  const float* x    = (const float*)d_in[0];
  const int*   ei   = (const int*)d_in[1];   // [2][B][N][K]; plane 0
  const float* W    = (const float*)d_in[2];
  const float* bias = (const float*)d_in[3];
  float* out = (float*)d_out;
  unsigned short* h = (unsigned short*)d_ws;  // B*N*COUT*2 = 16 MB bf16

  gemm_relu_k<<<dim3(B_ * N_ / 64), 256, 0, stream>>>(x, W, h);
  aggr_k<<<dim3(B_ * N_ / 64), 256, 0, stream>>>(h, ei, bias, out);
}